// Round 4
// baseline (1974.559 us; speedup 1.0000x reference)
//
#include <hip/hip_runtime.h>
#include <hip/hip_cooperative_groups.h>
#include <math.h>

namespace cg = cooperative_groups;

#define NN 10000
#define NE 100000
#define CC 6
#define LL 6
#define BB 16
#define FUNC_LO 100
#define FUNC_HI 9900
#define EPSF 1e-5f
#define NSLOT 64

struct Slot { double s1, s2; double pad[6]; };  // 64B-padded

struct Params {
  const float *x, *w1v, *b1, *w2v, *b2, *w3v, *b3, *gamma, *beta;
  const int *src, *dst, *w2r, *w3r, *w3c;
  float *out;
  int *row_start, *counts, *fill, *csr;
  float *xT, *h, *z2f, *z3;
  Slot *part, *baseS;
  int F, Ksel;
};

__device__ __forceinline__ float eluf(float x){ return x > 0.0f ? x : expm1f(x); }

__device__ void block_add_slot(double a, double q, Slot* sl){
  __shared__ double sb1[4], sb2[4];
  #pragma unroll
  for(int off=32;off;off>>=1){ a+=__shfl_down(a,off); q+=__shfl_down(q,off); }
  int wid = threadIdx.x>>6;
  if((threadIdx.x&63)==0){ sb1[wid]=a; sb2[wid]=q; }
  __syncthreads();
  if(threadIdx.x==0){
    double A=sb1[0]+sb1[1]+sb1[2]+sb1[3];
    double Q=sb2[0]+sb2[1]+sb2[2]+sb2[3];
    if(A!=0.0) atomicAdd(&sl->s1,A);
    if(Q!=0.0) atomicAdd(&sl->s2,Q);
  }
  __syncthreads();
}

// Every block derives BN params from the 64 partial slots + 64 base slots.
__device__ void bn_params(const Slot* part, const Slot* baseS, float* m, float* inv){
  __shared__ double s_mv[2];
  if(threadIdx.x < NSLOT){
    double a = part[threadIdx.x].s1 + baseS[threadIdx.x].s1;
    double q = part[threadIdx.x].s2 + baseS[threadIdx.x].s2;
    #pragma unroll
    for(int off=32;off;off>>=1){ a+=__shfl_down(a,off); q+=__shfl_down(q,off); }
    if(threadIdx.x==0){
      const double cnt = (double)NE*(double)BB;
      double md = a/cnt, vd = q/cnt - md*md;
      s_mv[0]=md; s_mv[1]=1.0/sqrt(vd+(double)EPSF);
    }
  }
  __syncthreads();
  *m=(float)s_mv[0]; *inv=(float)s_mv[1];
  __syncthreads();
}

// P1: transpose x -> xT, dst histogram, base BN sums (non-func-src edges keep
// z3 = b3[e] every layer; their BN contribution is constant).
__device__ void phase_P1(const Params& p, int tid, int nt){
  for(int i=tid;i<NN*BB;i+=nt){ int n=i>>4, b=i&15; p.xT[i]=p.x[b*NN+n]; }
  double a=0.0,q=0.0;
  for(int e=tid;e<NE;e+=nt){
    atomicAdd(&p.counts[p.dst[e]],1);
    int s=p.src[e];
    if(!(s>=FUNC_LO && s<FUNC_HI)){ double v=(double)p.b3[e]; a+=v; q+=v*v; }
  }
  block_add_slot(a*BB, q*BB, &p.baseS[blockIdx.x&(NSLOT-1)]);
}

// P2: exclusive scan of counts (block 0 only; 256 thr x 40 nodes).
__device__ void phase_scan(const Params& p){
  if(blockIdx.x!=0) return;
  __shared__ int s_scan[256];
  const int CH=(NN+255)/256;
  int t=threadIdx.x, base=t*CH, s=0;
  for(int k=0;k<CH;k++){ int i=base+k; if(i<NN) s+=p.counts[i]; }
  s_scan[t]=s; __syncthreads();
  for(int off=1;off<256;off<<=1){
    int v=(t>=off)?s_scan[t-off]:0; __syncthreads();
    s_scan[t]+=v; __syncthreads();
  }
  int run=s_scan[t]-s;
  for(int k=0;k<CH;k++){ int i=base+k; if(i<NN){ p.row_start[i]=run; run+=p.counts[i]; } }
  if(t==255) p.row_start[NN]=s_scan[255];
}

__device__ void phase_fill(const Params& p, int tid, int nt){
  for(int e=tid;e<NE;e+=nt){
    int n=p.dst[e];
    int pos=p.row_start[n]+atomicAdd(&p.fill[n],1);
    p.csr[pos]=e;
  }
}

// A_l: apply BN_{l-1}+residual to h in place (func-dst edges, inline with the
// CSR gather; out-dst edges in an extra range), then W1+ELU+W2+ELU -> z2f.
// l==0 reads x0 from xT; l==1 writes h's first value (x0 + BN_0).
__device__ void phase_A(const Params& p, int l, int tid, int nt){
  float m=0.f, inv=0.f, g=0.f, be=0.f;
  if(l>0){
    bn_params(p.part+(l-1)*NSLOT, p.baseS, &m, &inv);
    g=p.gamma[l-1]; be=p.beta[l-1];
  }
  const int FB = p.F*BB;
  const int outBeg = p.row_start[FUNC_HI];
  const int nOutE  = p.row_start[NN] - outBeg;
  const int totalA = FB + ((l>0)? nOutE*BB : 0);
  for(int t=tid;t<totalA;t+=nt){
    if(t<FB){
      int fi=t>>4, b=t&15;
      int n=p.w2r[fi*36]/CC;
      float acc[CC];
      #pragma unroll
      for(int i=0;i<CC;i++) acc[i]=p.b1[n*CC+i];
      int beg=p.row_start[n], end=p.row_start[n+1];
      for(int pp=beg;pp<end;++pp){
        int e=p.csr[pp];
        int s=p.src[e];
        float hv;
        if(l==0){
          hv = p.xT[s*BB+b];
        } else {
          float zb=(s>=FUNC_LO&&s<FUNC_HI)? p.z3[e*BB+b] : p.b3[e];
          float hb=(l==1)? p.xT[s*BB+b] : p.h[e*BB+b];
          hv = hb + (zb-m)*inv*g+be;
          p.h[e*BB+b]=hv;
        }
        const float* w=&p.w1v[e*CC];
        #pragma unroll
        for(int i=0;i<CC;i++) acc[i]+=hv*w[i];
      }
      #pragma unroll
      for(int i=0;i<CC;i++) acc[i]=eluf(acc[i]);
      const float* W2=&p.w2v[fi*36];
      #pragma unroll
      for(int j=0;j<CC;j++){
        float o=p.b2[n*CC+j];
        #pragma unroll
        for(int i=0;i<CC;i++) o+=acc[i]*W2[i*CC+j];
        p.z2f[(fi*CC+j)*BB+b]=eluf(o);
      }
    } else {
      int q=t-FB; int oi=q>>4, b=q&15;
      int e=p.csr[outBeg+oi];
      int s=p.src[e];
      float zb=(s>=FUNC_LO&&s<FUNC_HI)? p.z3[e*BB+b] : p.b3[e];
      float hb=(l==1)? p.xT[s*BB+b] : p.h[e*BB+b];
      p.h[e*BB+b]=hb+(zb-m)*inv*g+be;
    }
  }
}

// B_l: z3[e] = b3[e] + z2f[src-block]*w3 for selected edges; partial BN sums.
__device__ void phase_B(const Params& p, int l, int tid, int nt){
  double a=0.0,q=0.0;
  const int KB=p.Ksel*BB;
  for(int t=tid;t<KB;t+=nt){
    int k=t>>4, b=t&15;
    int e=p.w3c[k*CC];
    int fi=p.w3r[k*CC]/CC - FUNC_LO;
    float o=p.b3[e];
    const float* w=&p.w3v[k*CC];
    const float* z2=&p.z2f[fi*CC*BB + b];
    #pragma unroll
    for(int i=0;i<CC;i++) o += z2[i*BB]*w[i];
    p.z3[e*BB+b]=o;
    a+=o; q+=(double)o*o;
  }
  block_add_slot(a,q,&p.part[l*NSLOT+(blockIdx.x&(NSLOT-1))]);
}

// out: apply BN_{L-1} inline to out-dst edges, sum per output node, /L.
__device__ void phase_out(const Params& p, int tid, int nt){
  float m,inv;
  bn_params(p.part+(LL-1)*NSLOT, p.baseS, &m, &inv);
  float g=p.gamma[LL-1], be=p.beta[LL-1];
  for(int idx=tid;idx<BB*NN;idx+=nt){
    int b=idx/NN, n=idx-b*NN;
    float acc=0.f;
    if(n>=FUNC_HI){
      int beg=p.row_start[n], end=p.row_start[n+1];
      for(int pp=beg;pp<end;++pp){
        int e=p.csr[pp];
        int s=p.src[e];
        float zb=(s>=FUNC_LO&&s<FUNC_HI)? p.z3[e*BB+b] : p.b3[e];
        acc += p.h[e*BB+b] + (zb-m)*inv*g+be;
      }
      acc *= (1.0f/(float)LL);
    }
    p.out[idx]=acc;
  }
}

__global__ __launch_bounds__(256) void k_mega(Params p){
  cg::grid_group gg = cg::this_grid();
  const int tid = blockIdx.x*blockDim.x + threadIdx.x;
  const int nt  = gridDim.x*blockDim.x;
  phase_P1(p, tid, nt);   gg.sync();
  phase_scan(p);          gg.sync();
  phase_fill(p, tid, nt); gg.sync();
  for(int l=0;l<LL;l++){
    phase_A(p, l, tid, nt); gg.sync();
    phase_B(p, l, tid, nt); gg.sync();
  }
  phase_out(p, tid, nt);
}

// ---- fallback wrappers (used only if cooperative launch is unavailable) ----
__global__ __launch_bounds__(256) void kw_P1(Params p){ phase_P1(p, blockIdx.x*256+threadIdx.x, gridDim.x*256); }
__global__ __launch_bounds__(256) void kw_scan(Params p){ phase_scan(p); }
__global__ __launch_bounds__(256) void kw_fill(Params p){ phase_fill(p, blockIdx.x*256+threadIdx.x, gridDim.x*256); }
__global__ __launch_bounds__(256) void kw_A(Params p, int l){ phase_A(p, l, blockIdx.x*256+threadIdx.x, gridDim.x*256); }
__global__ __launch_bounds__(256) void kw_B(Params p, int l){ phase_B(p, l, blockIdx.x*256+threadIdx.x, gridDim.x*256); }
__global__ __launch_bounds__(256) void kw_out(Params p){ phase_out(p, blockIdx.x*256+threadIdx.x, gridDim.x*256); }

extern "C" void kernel_launch(void* const* d_in, const int* in_sizes, int n_in,
                              void* d_out, int out_size, void* d_ws, size_t ws_size,
                              hipStream_t stream){
  Params p;
  p.x    =(const float*)d_in[0];
  p.src  =(const int*)  d_in[1];
  p.dst  =(const int*)  d_in[2];
  p.w1v  =(const float*)d_in[6];
  p.b1   =(const float*)d_in[7];
  p.w2r  =(const int*)  d_in[8];
  p.w2v  =(const float*)d_in[10];
  p.b2   =(const float*)d_in[11];
  p.w3r  =(const int*)  d_in[12];
  p.w3c  =(const int*)  d_in[13];
  p.w3v  =(const float*)d_in[14];
  p.b3   =(const float*)d_in[15];
  p.gamma=(const float*)d_in[16];
  p.beta =(const float*)d_in[17];
  p.out  =(float*)d_out;
  p.F    = in_sizes[8]/36;
  p.Ksel = in_sizes[12]/CC;

  char* ws=(char*)d_ws; size_t off=0;
  auto alloc=[&](size_t bytes)->char*{
    char* q=ws+off; off=(off+bytes+255)&~(size_t)255; return q;
  };
  p.row_start=(int*)  alloc((NN+1)*sizeof(int));
  p.csr      =(int*)  alloc(NE*sizeof(int));
  p.xT       =(float*)alloc((size_t)NN*BB*sizeof(float));
  p.h        =(float*)alloc((size_t)NE*BB*sizeof(float));
  p.z2f      =(float*)alloc((size_t)p.F*CC*BB*sizeof(float));
  p.z3       =(float*)alloc((size_t)NE*BB*sizeof(float));
  // zero-initialized block (single memset): counts, fill, part, baseS
  p.counts   =(int*)  alloc(NN*sizeof(int));
  p.fill     =(int*)  alloc(NN*sizeof(int));
  p.part     =(Slot*) alloc((size_t)LL*NSLOT*sizeof(Slot));
  p.baseS    =(Slot*) alloc((size_t)NSLOT*sizeof(Slot));
  (void)ws_size; (void)n_in; (void)out_size;

  size_t zspan = (char*)(p.baseS+NSLOT) - (char*)p.counts;
  hipMemsetAsync(p.counts, 0, zspan, stream);

  int ncu=0, dev=0;
  hipGetDevice(&dev);
  if(hipDeviceGetAttribute(&ncu, hipDeviceAttributeMultiprocessorCount, dev)!=hipSuccess || ncu<=0)
    ncu=256;
  int maxb=0;
  if(hipOccupancyMaxActiveBlocksPerMultiprocessor(&maxb, (const void*)k_mega, 256, 0)!=hipSuccess || maxb<1)
    maxb=1;
  if(maxb>4) maxb=4;
  int grid = maxb*ncu;

  void* args[]={ (void*)&p };
  hipError_t err = hipLaunchCooperativeKernel((const void*)k_mega, dim3(grid), dim3(256),
                                              args, 0, stream);
  if(err != hipSuccess){
    // Fallback: same phases as plain kernels.
    kw_P1  <<<512,256,0,stream>>>(p);
    kw_scan<<<1,  256,0,stream>>>(p);
    kw_fill<<<512,256,0,stream>>>(p);
    for(int l=0;l<LL;l++){
      kw_A<<<1024,256,0,stream>>>(p,l);
      kw_B<<<1024,256,0,stream>>>(p,l);
    }
    kw_out<<<640,256,0,stream>>>(p);
  }
}

// Round 5
// 284.634 us; speedup vs baseline: 6.9372x; 6.9372x over previous
//
#include <hip/hip_runtime.h>
#include <math.h>

#define NN 10000
#define NE 100000
#define CC 6
#define LL 6
#define BB 16
#define FUNC_LO 100
#define FUNC_HI 9900
#define EPSF 1e-5f
#define NSLOT 64

struct Slot { double s1, s2; double pad[6]; };  // 64B-padded

struct Params {
  const float *x, *w1v, *b1, *w2v, *b2, *w3v, *b3, *gamma, *beta;
  const int *src, *dst, *w2r, *w3r, *w3c;
  float *out;
  int *row_start, *counts, *fill, *csr;
  float *xT, *h, *z2f, *z3;
  Slot *part, *baseS;
  int F, Ksel;
};

__device__ __forceinline__ float eluf(float x){ return x > 0.0f ? x : expm1f(x); }

__device__ void block_add_slot(double a, double q, Slot* sl){
  __shared__ double sb1[4], sb2[4];
  #pragma unroll
  for(int off=32;off;off>>=1){ a+=__shfl_down(a,off); q+=__shfl_down(q,off); }
  int wid = threadIdx.x>>6;
  if((threadIdx.x&63)==0){ sb1[wid]=a; sb2[wid]=q; }
  __syncthreads();
  if(threadIdx.x==0){
    double A=sb1[0]+sb1[1]+sb1[2]+sb1[3];
    double Q=sb2[0]+sb2[1]+sb2[2]+sb2[3];
    if(A!=0.0) atomicAdd(&sl->s1,A);
    if(Q!=0.0) atomicAdd(&sl->s2,Q);
  }
  __syncthreads();
}

// Every block derives BN params from the 64 partial slots + 64 base slots.
__device__ void bn_params(const Slot* part, const Slot* baseS, float* m, float* inv){
  __shared__ double s_mv[2];
  if(threadIdx.x < NSLOT){
    double a = part[threadIdx.x].s1 + baseS[threadIdx.x].s1;
    double q = part[threadIdx.x].s2 + baseS[threadIdx.x].s2;
    #pragma unroll
    for(int off=32;off;off>>=1){ a+=__shfl_down(a,off); q+=__shfl_down(q,off); }
    if(threadIdx.x==0){
      const double cnt = (double)NE*(double)BB;
      double md = a/cnt, vd = q/cnt - md*md;
      s_mv[0]=md; s_mv[1]=1.0/sqrt(vd+(double)EPSF);
    }
  }
  __syncthreads();
  *m=(float)s_mv[0]; *inv=(float)s_mv[1];
  __syncthreads();
}

// P1: transpose x -> xT, dst histogram, base BN sums (non-func-src edges keep
// z3 = b3[e] every layer; their BN contribution is constant).
__global__ __launch_bounds__(256) void kw_P1(Params p){
  int tid = blockIdx.x*256 + threadIdx.x, nt = gridDim.x*256;
  for(int i=tid;i<NN*BB;i+=nt){ int n=i>>4, b=i&15; p.xT[i]=p.x[b*NN+n]; }
  double a=0.0,q=0.0;
  for(int e=tid;e<NE;e+=nt){
    atomicAdd(&p.counts[p.dst[e]],1);
    int s=p.src[e];
    if(!(s>=FUNC_LO && s<FUNC_HI)){ double v=(double)p.b3[e]; a+=v; q+=v*v; }
  }
  block_add_slot(a*BB, q*BB, &p.baseS[blockIdx.x&(NSLOT-1)]);
}

// Exclusive scan of counts (single block; 256 thr x 40 nodes serial+LDS scan).
__global__ __launch_bounds__(256) void kw_scan(Params p){
  __shared__ int s_scan[256];
  const int CH=(NN+255)/256;
  int t=threadIdx.x, base=t*CH, s=0;
  for(int k=0;k<CH;k++){ int i=base+k; if(i<NN) s+=p.counts[i]; }
  s_scan[t]=s; __syncthreads();
  for(int off=1;off<256;off<<=1){
    int v=(t>=off)?s_scan[t-off]:0; __syncthreads();
    s_scan[t]+=v; __syncthreads();
  }
  int run=s_scan[t]-s;
  for(int k=0;k<CH;k++){ int i=base+k; if(i<NN){ p.row_start[i]=run; run+=p.counts[i]; } }
  if(t==255) p.row_start[NN]=s_scan[255];
}

__global__ __launch_bounds__(256) void kw_fill(Params p){
  int tid = blockIdx.x*256 + threadIdx.x, nt = gridDim.x*256;
  for(int e=tid;e<NE;e+=nt){
    int n=p.dst[e];
    int pos=p.row_start[n]+atomicAdd(&p.fill[n],1);
    p.csr[pos]=e;
  }
}

// A_l: apply BN_{l-1}+residual to h in place (func-dst edges, inline with the
// CSR gather; out-dst edges in an extra range), then W1+ELU+W2+ELU -> z2f.
// l==0 reads x0 from xT; l==1 writes h's first value (x0 + BN_0).
__global__ __launch_bounds__(256) void kw_A(Params p, int l){
  int tid = blockIdx.x*256 + threadIdx.x, nt = gridDim.x*256;
  float m=0.f, inv=0.f, g=0.f, be=0.f;
  if(l>0){
    bn_params(p.part+(l-1)*NSLOT, p.baseS, &m, &inv);
    g=p.gamma[l-1]; be=p.beta[l-1];
  }
  const int FB = p.F*BB;
  const int outBeg = p.row_start[FUNC_HI];
  const int nOutE  = p.row_start[NN] - outBeg;
  const int totalA = FB + ((l>0)? nOutE*BB : 0);
  for(int t=tid;t<totalA;t+=nt){
    if(t<FB){
      int fi=t>>4, b=t&15;
      int n=p.w2r[fi*36]/CC;
      float acc[CC];
      #pragma unroll
      for(int i=0;i<CC;i++) acc[i]=p.b1[n*CC+i];
      int beg=p.row_start[n], end=p.row_start[n+1];
      for(int pp=beg;pp<end;++pp){
        int e=p.csr[pp];
        int s=p.src[e];
        float hv;
        if(l==0){
          hv = p.xT[s*BB+b];
        } else {
          float zb=(s>=FUNC_LO&&s<FUNC_HI)? p.z3[e*BB+b] : p.b3[e];
          float hb=(l==1)? p.xT[s*BB+b] : p.h[e*BB+b];
          hv = hb + (zb-m)*inv*g+be;
          p.h[e*BB+b]=hv;
        }
        const float* w=&p.w1v[e*CC];
        #pragma unroll
        for(int i=0;i<CC;i++) acc[i]+=hv*w[i];
      }
      #pragma unroll
      for(int i=0;i<CC;i++) acc[i]=eluf(acc[i]);
      const float* W2=&p.w2v[fi*36];
      #pragma unroll
      for(int j=0;j<CC;j++){
        float o=p.b2[n*CC+j];
        #pragma unroll
        for(int i=0;i<CC;i++) o+=acc[i]*W2[i*CC+j];
        p.z2f[(fi*CC+j)*BB+b]=eluf(o);
      }
    } else {
      int q=t-FB; int oi=q>>4, b=q&15;
      int e=p.csr[outBeg+oi];
      int s=p.src[e];
      float zb=(s>=FUNC_LO&&s<FUNC_HI)? p.z3[e*BB+b] : p.b3[e];
      float hb=(l==1)? p.xT[s*BB+b] : p.h[e*BB+b];
      p.h[e*BB+b]=hb+(zb-m)*inv*g+be;
    }
  }
}

// B_l: z3[e] = b3[e] + z2f[src-block]*w3 for selected edges; partial BN sums.
__global__ __launch_bounds__(256) void kw_B(Params p, int l){
  int tid = blockIdx.x*256 + threadIdx.x, nt = gridDim.x*256;
  double a=0.0,q=0.0;
  const int KB=p.Ksel*BB;
  for(int t=tid;t<KB;t+=nt){
    int k=t>>4, b=t&15;
    int e=p.w3c[k*CC];
    int fi=p.w3r[k*CC]/CC - FUNC_LO;
    float o=p.b3[e];
    const float* w=&p.w3v[k*CC];
    const float* z2=&p.z2f[fi*CC*BB + b];
    #pragma unroll
    for(int i=0;i<CC;i++) o += z2[i*BB]*w[i];
    p.z3[e*BB+b]=o;
    a+=o; q+=(double)o*o;
  }
  block_add_slot(a,q,&p.part[l*NSLOT+(blockIdx.x&(NSLOT-1))]);
}

// out: apply BN_{L-1} inline to out-dst edges, sum per output node, /L.
__global__ __launch_bounds__(256) void kw_out(Params p){
  int tid = blockIdx.x*256 + threadIdx.x, nt = gridDim.x*256;
  float m,inv;
  bn_params(p.part+(LL-1)*NSLOT, p.baseS, &m, &inv);
  float g=p.gamma[LL-1], be=p.beta[LL-1];
  for(int idx=tid;idx<BB*NN;idx+=nt){
    int b=idx/NN, n=idx-b*NN;
    float acc=0.f;
    if(n>=FUNC_HI){
      int beg=p.row_start[n], end=p.row_start[n+1];
      for(int pp=beg;pp<end;++pp){
        int e=p.csr[pp];
        int s=p.src[e];
        float zb=(s>=FUNC_LO&&s<FUNC_HI)? p.z3[e*BB+b] : p.b3[e];
        acc += p.h[e*BB+b] + (zb-m)*inv*g+be;
      }
      acc *= (1.0f/(float)LL);
    }
    p.out[idx]=acc;
  }
}

extern "C" void kernel_launch(void* const* d_in, const int* in_sizes, int n_in,
                              void* d_out, int out_size, void* d_ws, size_t ws_size,
                              hipStream_t stream){
  Params p;
  p.x    =(const float*)d_in[0];
  p.src  =(const int*)  d_in[1];
  p.dst  =(const int*)  d_in[2];
  p.w1v  =(const float*)d_in[6];
  p.b1   =(const float*)d_in[7];
  p.w2r  =(const int*)  d_in[8];
  p.w2v  =(const float*)d_in[10];
  p.b2   =(const float*)d_in[11];
  p.w3r  =(const int*)  d_in[12];
  p.w3c  =(const int*)  d_in[13];
  p.w3v  =(const float*)d_in[14];
  p.b3   =(const float*)d_in[15];
  p.gamma=(const float*)d_in[16];
  p.beta =(const float*)d_in[17];
  p.out  =(float*)d_out;
  p.F    = in_sizes[8]/36;
  p.Ksel = in_sizes[12]/CC;

  char* ws=(char*)d_ws; size_t off=0;
  auto alloc=[&](size_t bytes)->char*{
    char* q=ws+off; off=(off+bytes+255)&~(size_t)255; return q;
  };
  p.row_start=(int*)  alloc((NN+1)*sizeof(int));
  p.csr      =(int*)  alloc(NE*sizeof(int));
  p.xT       =(float*)alloc((size_t)NN*BB*sizeof(float));
  p.h        =(float*)alloc((size_t)NE*BB*sizeof(float));
  p.z2f      =(float*)alloc((size_t)p.F*CC*BB*sizeof(float));
  p.z3       =(float*)alloc((size_t)NE*BB*sizeof(float));
  // zero-initialized block (single memset): counts, fill, part, baseS
  p.counts   =(int*)  alloc(NN*sizeof(int));
  p.fill     =(int*)  alloc(NN*sizeof(int));
  p.part     =(Slot*) alloc((size_t)LL*NSLOT*sizeof(Slot));
  p.baseS    =(Slot*) alloc((size_t)NSLOT*sizeof(Slot));
  (void)ws_size; (void)n_in; (void)out_size;

  size_t zspan = (char*)(p.baseS+NSLOT) - (char*)p.counts;
  hipMemsetAsync(p.counts, 0, zspan, stream);

  const int gridA   = (p.F*BB + 100*BB*BB + 255)/256;      // func range + out-edge range headroom
  const int gridB   = (p.Ksel*BB + 255)/256;
  const int gridE   = (NE + 255)/256;

  kw_P1  <<<512,  256,0,stream>>>(p);
  kw_scan<<<1,    256,0,stream>>>(p);
  kw_fill<<<gridE,256,0,stream>>>(p);
  for(int l=0;l<LL;l++){
    kw_A<<<gridA,256,0,stream>>>(p,l);
    kw_B<<<gridB,256,0,stream>>>(p,l);
  }
  kw_out<<<(BB*NN+255)/256,256,0,stream>>>(p);
}